// Round 2
// baseline (4550.453 us; speedup 1.0000x reference)
//
#include <hip/hip_runtime.h>
#include <hip/hip_bf16.h>
#include <stdint.h>

typedef __bf16 bf16_t;
typedef bf16_t bf16x8 __attribute__((ext_vector_type(8)));
typedef float f32x4 __attribute__((ext_vector_type(4)));

#define NN 10000

__device__ __forceinline__ unsigned short f2b(float f) {
  union { float f; unsigned int i; } c; c.f = f;
  unsigned int x = c.i;
  x += 0x7FFFu + ((x >> 16) & 1u);
  return (unsigned short)(x >> 16);
}

// ---------------- degree ----------------
__global__ void deg_init(float* deg, int n) {
  int i = blockIdx.x * 256 + threadIdx.x;
  if (i < n) deg[i] = 1.0f;
}
__global__ void deg_accum(float* deg, const int* __restrict__ dst, int E) {
  int e = blockIdx.x * 256 + threadIdx.x;
  if (e < E) atomicAdd(&deg[dst[e]], 1.0f);
}
__global__ void deg_rsqrt(float* deg, int n) {
  int i = blockIdx.x * 256 + threadIdx.x;
  if (i < n) deg[i] = rsqrtf(deg[i]);
}

// ------------- weight transposes: fp32 [K][N] -> bf16 [N][K] -------------
__global__ void transpose512(const float* __restrict__ W, unsigned short* __restrict__ Wt) {
  int t = blockIdx.x * 256 + threadIdx.x;   // t = n*512 + k, coalesced write
  int nn = t >> 9, k = t & 511;
  Wt[t] = f2b(W[k * 512 + nn]);
}
__global__ void transpose_wc(const float* __restrict__ Wc, unsigned short* __restrict__ Wct) {
  int t = blockIdx.x * 256 + threadIdx.x;   // t over 128*512
  int nn = t >> 9, k = t & 511;
  Wct[t] = (nn < 100) ? f2b(Wc[k * 100 + nn]) : (unsigned short)0;
}

// ---- GEMM: C[M][N] (fp32) = A[M][512] (fp32, staged->bf16) * Bt[N][512]^T (bf16) ----
__device__ __forceinline__ f32x4 mfma16(bf16x8 a, bf16x8 b, f32x4 c) {
  return __builtin_amdgcn_mfma_f32_16x16x32_bf16(a, b, c, 0, 0, 0);
}
__device__ __forceinline__ uint4 cvt8(float4 a, float4 b) {
  uint4 r;
  r.x = (unsigned int)f2b(a.x) | ((unsigned int)f2b(a.y) << 16);
  r.y = (unsigned int)f2b(a.z) | ((unsigned int)f2b(a.w) << 16);
  r.z = (unsigned int)f2b(b.x) | ((unsigned int)f2b(b.y) << 16);
  r.w = (unsigned int)f2b(b.z) | ((unsigned int)f2b(b.w) << 16);
  return r;
}

template <bool BIAS>
__global__ __launch_bounds__(256)
void gemm_bt(const float* __restrict__ A, const unsigned short* __restrict__ Bt,
             float* __restrict__ C, const float* __restrict__ bias,
             int M, int Ncols, int ldc)
{
  __shared__ __align__(16) unsigned short As[128 * 32];
  __shared__ __align__(16) unsigned short Bs[128 * 32];
  const int tid = threadIdx.x;
  const int lane = tid & 63;
  const int wm = (tid >> 6) >> 1;
  const int wn = (tid >> 6) & 1;
  const int tm = blockIdx.x, tn = blockIdx.y;
  const int quad = lane >> 4, l15 = lane & 15;

  // staging: each thread covers 8 k-elements of one row in each 64-row half
  const int r0 = tid >> 2, kc = tid & 3;
  int ga0 = tm * 128 + r0;       if (ga0 > M - 1) ga0 = M - 1;
  int ga1 = tm * 128 + 64 + r0;  if (ga1 > M - 1) ga1 = M - 1;
  const int gb0 = tn * 128 + r0;
  const int gb1 = tn * 128 + 64 + r0;

  f32x4 acc[4][4];
  #pragma unroll
  for (int i = 0; i < 4; i++)
    #pragma unroll
    for (int j = 0; j < 4; j++) {
      f32x4 z = {0.f, 0.f, 0.f, 0.f};
      acc[i][j] = z;
    }

  for (int k0 = 0; k0 < 512; k0 += 32) {
    const float4* a0p = (const float4*)&A[(size_t)ga0 * 512 + k0 + kc * 8];
    const float4* a1p = (const float4*)&A[(size_t)ga1 * 512 + k0 + kc * 8];
    float4 a00 = a0p[0], a01 = a0p[1];
    float4 a10 = a1p[0], a11 = a1p[1];
    const uint4 bv0 = *(const uint4*)&Bt[(size_t)gb0 * 512 + k0 + kc * 8];
    const uint4 bv1 = *(const uint4*)&Bt[(size_t)gb1 * 512 + k0 + kc * 8];
    __syncthreads();
    *(uint4*)&As[r0 * 32 + kc * 8] = cvt8(a00, a01);
    *(uint4*)&As[(64 + r0) * 32 + kc * 8] = cvt8(a10, a11);
    *(uint4*)&Bs[r0 * 32 + kc * 8] = bv0;
    *(uint4*)&Bs[(64 + r0) * 32 + kc * 8] = bv1;
    __syncthreads();

    bf16x8 af[4], bfr[4];
    #pragma unroll
    for (int i = 0; i < 4; i++) {
      af[i]  = *(const bf16x8*)&As[(wm * 64 + i * 16 + l15) * 32 + quad * 8];
      bfr[i] = *(const bf16x8*)&Bs[(wn * 64 + i * 16 + l15) * 32 + quad * 8];
    }
    #pragma unroll
    for (int i = 0; i < 4; i++)
      #pragma unroll
      for (int j = 0; j < 4; j++)
        acc[i][j] = mfma16(af[i], bfr[j], acc[i][j]);
  }

  // epilogue: C/D layout col=lane&15, row=quad*4+reg  [m89-verified]
  #pragma unroll
  for (int i = 0; i < 4; i++) {
    const int row_base = tm * 128 + wm * 64 + i * 16 + quad * 4;
    #pragma unroll
    for (int j = 0; j < 4; j++) {
      const int col = tn * 128 + wn * 64 + j * 16 + l15;
      if (col < Ncols) {
        float badd = BIAS ? bias[col] : 0.f;
        #pragma unroll
        for (int r = 0; r < 4; r++) {
          int row = row_base + r;
          if (row < M) C[(size_t)row * ldc + col] = acc[i][j][r] + badd;
        }
      }
    }
  }
}

// ------------- agg = h * dinv^2 + bias  (all fp32) -------------
__global__ void agg_init(const float* __restrict__ h, const float* __restrict__ dinv,
                         const float* __restrict__ b, float* __restrict__ agg, int n) {
  int t = blockIdx.x * 256 + threadIdx.x;
  if (t >= n * 64) return;
  int node = t >> 6, c8 = (t & 63) << 3;
  float s = dinv[node]; s *= s;
  const float4* hp = (const float4*)&h[(size_t)node * 512 + c8];
  const float4* bp = (const float4*)&b[c8];
  float4 h0 = hp[0], h1 = hp[1];
  float4 b0 = bp[0], b1 = bp[1];
  float4* ap = (float4*)&agg[(size_t)node * 512 + c8];
  ap[0] = make_float4(h0.x * s + b0.x, h0.y * s + b0.y, h0.z * s + b0.z, h0.w * s + b0.w);
  ap[1] = make_float4(h1.x * s + b1.x, h1.y * s + b1.y, h1.z * s + b1.z, h1.w * s + b1.w);
}

// ------------- per-edge scatter: one wave per edge (fp32) -------------
__global__ void edge_scatter(const float* __restrict__ h, const float* __restrict__ dinv,
                             const int* __restrict__ src, const int* __restrict__ dst,
                             float* __restrict__ agg, int E) {
  int e = blockIdx.x * 4 + (threadIdx.x >> 6);
  if (e >= E) return;
  int lane = threadIdx.x & 63;
  int s = src[e], d = dst[e];
  float norm = dinv[s] * dinv[d];
  const float4* hp = (const float4*)&h[(size_t)s * 512 + lane * 8];
  float4 h0 = hp[0], h1 = hp[1];
  float* ap = &agg[(size_t)d * 512 + lane * 8];
  atomicAdd(&ap[0], h0.x * norm);
  atomicAdd(&ap[1], h0.y * norm);
  atomicAdd(&ap[2], h0.z * norm);
  atomicAdd(&ap[3], h0.w * norm);
  atomicAdd(&ap[4], h1.x * norm);
  atomicAdd(&ap[5], h1.y * norm);
  atomicAdd(&ap[6], h1.z * norm);
  atomicAdd(&ap[7], h1.w * norm);
}

// ------------- in-place ReLU -------------
__global__ void relu_inplace(float* __restrict__ a, int n_vec4) {
  int t = blockIdx.x * 256 + threadIdx.x;
  if (t >= n_vec4) return;
  float4* p = (float4*)a + t;
  float4 v = *p;
  v.x = fmaxf(v.x, 0.f); v.y = fmaxf(v.y, 0.f);
  v.z = fmaxf(v.z, 0.f); v.w = fmaxf(v.w, 0.f);
  *p = v;
}

extern "C" void kernel_launch(void* const* d_in, const int* in_sizes, int n_in,
                              void* d_out, int out_size, void* d_ws, size_t ws_size,
                              hipStream_t stream) {
  const float* x  = (const float*)d_in[0];
  const int*   ei = (const int*)d_in[1];
  const float* W1 = (const float*)d_in[2];
  const float* b1 = (const float*)d_in[3];
  const float* W2 = (const float*)d_in[4];
  const float* b2 = (const float*)d_in[5];
  const float* Wc = (const float*)d_in[6];
  const float* bc = (const float*)d_in[7];
  float* out = (float*)d_out;

  const int n = NN;
  const int E = in_sizes[1] / 2;
  const int* src = ei;
  const int* dst = ei + E;

  // workspace layout (~42.1 MB)
  char* w = (char*)d_ws;
  float* dinv = (float*)w;                  w += 64 * 1024;
  unsigned short* W1t = (unsigned short*)w; w += 512 * 512 * 2;
  unsigned short* W2t = (unsigned short*)w; w += 512 * 512 * 2;
  unsigned short* Wct = (unsigned short*)w; w += 128 * 512 * 2;
  float* B1 = (float*)w;                    w += (size_t)n * 512 * 4;  // agg / hin
  float* B2 = (float*)w;                    w += (size_t)n * 512 * 4;  // h (pre-agg)

  const int nb_n  = (n + 255) / 256;
  const int nb_e  = (E + 255) / 256;
  const int nb_el = (n * 64 + 255) / 256;        // 8 floats per thread
  const int nb_r  = (n * 128 + 255) / 256;       // 4 floats per thread
  dim3 g1((n + 127) / 128, 4);
  dim3 g3((n + 127) / 128, 1);

  // degree -> dinv
  deg_init<<<nb_n, 256, 0, stream>>>(dinv, n);
  deg_accum<<<nb_e, 256, 0, stream>>>(dinv, dst, E);
  deg_rsqrt<<<nb_n, 256, 0, stream>>>(dinv, n);

  // weight transposes (fp32 -> bf16 [N][K])
  transpose512<<<512 * 512 / 256, 256, 0, stream>>>(W1, W1t);
  transpose512<<<512 * 512 / 256, 256, 0, stream>>>(W2, W2t);
  transpose_wc<<<128 * 512 / 256, 256, 0, stream>>>(Wc, Wct);

  // layer 1: h=B2, agg=B1
  gemm_bt<false><<<g1, 256, 0, stream>>>(x, W1t, B2, nullptr, n, 512, 512);
  agg_init<<<nb_el, 256, 0, stream>>>(B2, dinv, b1, B1, n);
  edge_scatter<<<(E + 3) / 4, 256, 0, stream>>>(B2, dinv, src, dst, B1, E);
  relu_inplace<<<nb_r, 256, 0, stream>>>(B1, n * 128);

  // layer 2: reads B1, h=B2, agg=B1 (B1 dead after gemm)
  gemm_bt<false><<<g1, 256, 0, stream>>>(B1, W2t, B2, nullptr, n, 512, 512);
  agg_init<<<nb_el, 256, 0, stream>>>(B2, dinv, b2, B1, n);
  edge_scatter<<<(E + 3) / 4, 256, 0, stream>>>(B2, dinv, src, dst, B1, E);

  // classifier: reads B1 -> d_out (fp32)
  gemm_bt<true><<<g3, 256, 0, stream>>>(B1, Wct, out, bc, n, 100, 100);
}

// Round 3
// 300.152 us; speedup vs baseline: 15.1605x; 15.1605x over previous
//
#include <hip/hip_runtime.h>
#include <hip/hip_bf16.h>
#include <stdint.h>

typedef __bf16 bf16_t;
typedef bf16_t bf16x8 __attribute__((ext_vector_type(8)));
typedef float f32x4 __attribute__((ext_vector_type(4)));

#define NN 10000

__device__ __forceinline__ unsigned short f2b(float f) {
  union { float f; unsigned int i; } c; c.f = f;
  unsigned int x = c.i;
  x += 0x7FFFu + ((x >> 16) & 1u);
  return (unsigned short)(x >> 16);
}

// ---------------- degree / CSR build ----------------
__global__ void edeg_zero(int* edeg, int n) {
  int i = blockIdx.x * 256 + threadIdx.x;
  if (i < n) edeg[i] = 0;
}
__global__ void edeg_accum(int* edeg, const int* __restrict__ dst, int E) {
  int e = blockIdx.x * 256 + threadIdx.x;
  if (e < E) atomicAdd(&edeg[dst[e]], 1);
}
// dinv = rsqrt(1 + in_deg); also re-zero edeg so it can serve as the fill cursor
__global__ void dinv_k(float* dinv, int* edeg, int n) {
  int i = blockIdx.x * 256 + threadIdx.x;
  if (i < n) { dinv[i] = rsqrtf(1.0f + (float)edeg[i]); edeg[i] = 0; }
}
// single-block exclusive scan of edeg -> rowstart[0..n], rowstart[n]=E
__global__ void csr_scan(const int* __restrict__ edeg, int* __restrict__ rowstart, int n) {
  __shared__ int partial[256];
  const int t = threadIdx.x;
  const int per = (n + 255) / 256;
  const int lo = t * per;
  const int hi = (lo + per < n) ? lo + per : n;
  int s = 0;
  for (int i = lo; i < hi; i++) s += edeg[i];
  partial[t] = s;
  __syncthreads();
  for (int off = 1; off < 256; off <<= 1) {
    int v = (t >= off) ? partial[t - off] : 0;
    __syncthreads();
    partial[t] += v;
    __syncthreads();
  }
  int run = (t > 0) ? partial[t - 1] : 0;   // exclusive prefix
  for (int i = lo; i < hi; i++) { rowstart[i] = run; run += edeg[i]; }
  if (t == 255) rowstart[n] = run;
}
__global__ void csr_fill(const int* __restrict__ src, const int* __restrict__ dst,
                         const float* __restrict__ dinv, const int* __restrict__ rowstart,
                         int* __restrict__ cursor, int* __restrict__ csr_src,
                         float* __restrict__ csr_norm, int E) {
  int e = blockIdx.x * 256 + threadIdx.x;
  if (e >= E) return;
  int s = src[e], d = dst[e];
  int pos = rowstart[d] + atomicAdd(&cursor[d], 1);
  csr_src[pos] = s;
  csr_norm[pos] = dinv[s] * dinv[d];
}

// ------------- weight transposes: fp32 [K][N] -> bf16 [N][K] -------------
__global__ void transpose512(const float* __restrict__ W, unsigned short* __restrict__ Wt) {
  int t = blockIdx.x * 256 + threadIdx.x;
  int nn = t >> 9, k = t & 511;
  Wt[t] = f2b(W[k * 512 + nn]);
}
__global__ void transpose_wc(const float* __restrict__ Wc, unsigned short* __restrict__ Wct) {
  int t = blockIdx.x * 256 + threadIdx.x;
  int nn = t >> 9, k = t & 511;
  Wct[t] = (nn < 100) ? f2b(Wc[k * 100 + nn]) : (unsigned short)0;
}

// ---- GEMM: C[M][N] (fp32) = A[M][512] (fp32, staged->bf16) * Bt[N][512]^T (bf16) ----
__device__ __forceinline__ f32x4 mfma16(bf16x8 a, bf16x8 b, f32x4 c) {
  return __builtin_amdgcn_mfma_f32_16x16x32_bf16(a, b, c, 0, 0, 0);
}
__device__ __forceinline__ uint4 cvt8(float4 a, float4 b) {
  uint4 r;
  r.x = (unsigned int)f2b(a.x) | ((unsigned int)f2b(a.y) << 16);
  r.y = (unsigned int)f2b(a.z) | ((unsigned int)f2b(a.w) << 16);
  r.z = (unsigned int)f2b(b.x) | ((unsigned int)f2b(b.y) << 16);
  r.w = (unsigned int)f2b(b.z) | ((unsigned int)f2b(b.w) << 16);
  return r;
}

template <bool BIAS>
__global__ __launch_bounds__(256)
void gemm_bt(const float* __restrict__ A, const unsigned short* __restrict__ Bt,
             float* __restrict__ C, const float* __restrict__ bias,
             int M, int Ncols, int ldc)
{
  __shared__ __align__(16) unsigned short As[128 * 32];
  __shared__ __align__(16) unsigned short Bs[128 * 32];
  const int tid = threadIdx.x;
  const int lane = tid & 63;
  const int wm = (tid >> 6) >> 1;
  const int wn = (tid >> 6) & 1;
  const int tm = blockIdx.x, tn = blockIdx.y;
  const int quad = lane >> 4, l15 = lane & 15;

  const int r0 = tid >> 2, kc = tid & 3;
  int ga0 = tm * 128 + r0;       if (ga0 > M - 1) ga0 = M - 1;
  int ga1 = tm * 128 + 64 + r0;  if (ga1 > M - 1) ga1 = M - 1;
  const int gb0 = tn * 128 + r0;
  const int gb1 = tn * 128 + 64 + r0;

  f32x4 acc[4][4];
  #pragma unroll
  for (int i = 0; i < 4; i++)
    #pragma unroll
    for (int j = 0; j < 4; j++) {
      f32x4 z = {0.f, 0.f, 0.f, 0.f};
      acc[i][j] = z;
    }

  for (int k0 = 0; k0 < 512; k0 += 32) {
    const float4* a0p = (const float4*)&A[(size_t)ga0 * 512 + k0 + kc * 8];
    const float4* a1p = (const float4*)&A[(size_t)ga1 * 512 + k0 + kc * 8];
    float4 a00 = a0p[0], a01 = a0p[1];
    float4 a10 = a1p[0], a11 = a1p[1];
    const uint4 bv0 = *(const uint4*)&Bt[(size_t)gb0 * 512 + k0 + kc * 8];
    const uint4 bv1 = *(const uint4*)&Bt[(size_t)gb1 * 512 + k0 + kc * 8];
    __syncthreads();
    *(uint4*)&As[r0 * 32 + kc * 8] = cvt8(a00, a01);
    *(uint4*)&As[(64 + r0) * 32 + kc * 8] = cvt8(a10, a11);
    *(uint4*)&Bs[r0 * 32 + kc * 8] = bv0;
    *(uint4*)&Bs[(64 + r0) * 32 + kc * 8] = bv1;
    __syncthreads();

    bf16x8 af[4], bfr[4];
    #pragma unroll
    for (int i = 0; i < 4; i++) {
      af[i]  = *(const bf16x8*)&As[(wm * 64 + i * 16 + l15) * 32 + quad * 8];
      bfr[i] = *(const bf16x8*)&Bs[(wn * 64 + i * 16 + l15) * 32 + quad * 8];
    }
    #pragma unroll
    for (int i = 0; i < 4; i++)
      #pragma unroll
      for (int j = 0; j < 4; j++)
        acc[i][j] = mfma16(af[i], bfr[j], acc[i][j]);
  }

  #pragma unroll
  for (int i = 0; i < 4; i++) {
    const int row_base = tm * 128 + wm * 64 + i * 16 + quad * 4;
    #pragma unroll
    for (int j = 0; j < 4; j++) {
      const int col = tn * 128 + wn * 64 + j * 16 + l15;
      if (col < Ncols) {
        float badd = BIAS ? bias[col] : 0.f;
        #pragma unroll
        for (int r = 0; r < 4; r++) {
          int row = row_base + r;
          if (row < M) C[(size_t)row * ldc + col] = acc[i][j][r] + badd;
        }
      }
    }
  }
}

// ------ gather aggregation: one wave per dst node, fused self-loop+bias(+ReLU) ------
template <bool RELU>
__global__ __launch_bounds__(256)
void gather_agg(const float* __restrict__ h, const float* __restrict__ dinv,
                const int* __restrict__ rowstart, const int* __restrict__ csr_src,
                const float* __restrict__ csr_norm, const float* __restrict__ bias,
                float* __restrict__ outbuf, int n)
{
  int node = blockIdx.x * 4 + (threadIdx.x >> 6);
  if (node >= n) return;
  const int lane = threadIdx.x & 63;
  const int c8 = lane * 8;

  float di = dinv[node];
  float s2 = di * di;
  const float4* hp = (const float4*)&h[(size_t)node * 512 + c8];
  const float4* bp = (const float4*)&bias[c8];
  float4 h0 = hp[0], h1 = hp[1];
  float4 b0 = bp[0], b1 = bp[1];
  float a0 = fmaf(h0.x, s2, b0.x), a1 = fmaf(h0.y, s2, b0.y);
  float a2 = fmaf(h0.z, s2, b0.z), a3 = fmaf(h0.w, s2, b0.w);
  float a4 = fmaf(h1.x, s2, b1.x), a5 = fmaf(h1.y, s2, b1.y);
  float a6 = fmaf(h1.z, s2, b1.z), a7 = fmaf(h1.w, s2, b1.w);

  const int jb = rowstart[node], je = rowstart[node + 1];
  for (int j = jb; j < je; ++j) {
    int s = csr_src[j];
    float nm = csr_norm[j];
    const float4* sp = (const float4*)&h[(size_t)s * 512 + c8];
    float4 v0 = sp[0], v1 = sp[1];
    a0 = fmaf(v0.x, nm, a0); a1 = fmaf(v0.y, nm, a1);
    a2 = fmaf(v0.z, nm, a2); a3 = fmaf(v0.w, nm, a3);
    a4 = fmaf(v1.x, nm, a4); a5 = fmaf(v1.y, nm, a5);
    a6 = fmaf(v1.z, nm, a6); a7 = fmaf(v1.w, nm, a7);
  }
  if (RELU) {
    a0 = fmaxf(a0, 0.f); a1 = fmaxf(a1, 0.f); a2 = fmaxf(a2, 0.f); a3 = fmaxf(a3, 0.f);
    a4 = fmaxf(a4, 0.f); a5 = fmaxf(a5, 0.f); a6 = fmaxf(a6, 0.f); a7 = fmaxf(a7, 0.f);
  }
  float4* op = (float4*)&outbuf[(size_t)node * 512 + c8];
  op[0] = make_float4(a0, a1, a2, a3);
  op[1] = make_float4(a4, a5, a6, a7);
}

extern "C" void kernel_launch(void* const* d_in, const int* in_sizes, int n_in,
                              void* d_out, int out_size, void* d_ws, size_t ws_size,
                              hipStream_t stream) {
  const float* x  = (const float*)d_in[0];
  const int*   ei = (const int*)d_in[1];
  const float* W1 = (const float*)d_in[2];
  const float* b1 = (const float*)d_in[3];
  const float* W2 = (const float*)d_in[4];
  const float* b2 = (const float*)d_in[5];
  const float* Wc = (const float*)d_in[6];
  const float* bc = (const float*)d_in[7];
  float* out = (float*)d_out;

  const int n = NN;
  const int E = in_sizes[1] / 2;
  const int* src = ei;
  const int* dst = ei + E;

  // workspace layout (~43.5 MB)
  char* w = (char*)d_ws;
  float* dinv = (float*)w;                  w += ((n * 4 + 255) / 256) * 256;
  int* edeg = (int*)w;                      w += ((n * 4 + 255) / 256) * 256;     // also CSR fill cursor
  int* rowstart = (int*)w;                  w += (((n + 1) * 4 + 255) / 256) * 256;
  int* csr_src = (int*)w;                   w += ((E * 4 + 255) / 256) * 256;
  float* csr_norm = (float*)w;              w += ((E * 4 + 255) / 256) * 256;
  unsigned short* W1t = (unsigned short*)w; w += 512 * 512 * 2;
  unsigned short* W2t = (unsigned short*)w; w += 512 * 512 * 2;
  unsigned short* Wct = (unsigned short*)w; w += 128 * 512 * 2;
  float* B1 = (float*)w;                    w += (size_t)n * 512 * 4;  // agg / hin
  float* B2 = (float*)w;                    w += (size_t)n * 512 * 4;  // h (pre-agg)

  const int nb_n = (n + 255) / 256;
  const int nb_e = (E + 255) / 256;
  dim3 g1((n + 127) / 128, 4);
  dim3 g3((n + 127) / 128, 1);
  const int nb_g = (n + 3) / 4;   // gather: 4 nodes (waves) per block

  // CSR build + dinv
  edeg_zero<<<nb_n, 256, 0, stream>>>(edeg, n);
  edeg_accum<<<nb_e, 256, 0, stream>>>(edeg, dst, E);
  csr_scan<<<1, 256, 0, stream>>>(edeg, rowstart, n);
  dinv_k<<<nb_n, 256, 0, stream>>>(dinv, edeg, n);   // also zeroes edeg -> cursor
  csr_fill<<<nb_e, 256, 0, stream>>>(src, dst, dinv, rowstart, edeg, csr_src, csr_norm, E);

  // weight transposes (fp32 -> bf16 [N][K])
  transpose512<<<512 * 512 / 256, 256, 0, stream>>>(W1, W1t);
  transpose512<<<512 * 512 / 256, 256, 0, stream>>>(W2, W2t);
  transpose_wc<<<128 * 512 / 256, 256, 0, stream>>>(Wc, Wct);

  // layer 1: h=B2, agg(->relu)=B1
  gemm_bt<false><<<g1, 256, 0, stream>>>(x, W1t, B2, nullptr, n, 512, 512);
  gather_agg<true><<<nb_g, 256, 0, stream>>>(B2, dinv, rowstart, csr_src, csr_norm, b1, B1, n);

  // layer 2: reads B1, h=B2, agg=B1
  gemm_bt<false><<<g1, 256, 0, stream>>>(B1, W2t, B2, nullptr, n, 512, 512);
  gather_agg<false><<<nb_g, 256, 0, stream>>>(B2, dinv, rowstart, csr_src, csr_norm, b2, B1, n);

  // classifier: reads B1 -> d_out (fp32)
  gemm_bt<true><<<g3, 256, 0, stream>>>(B1, Wct, out, bc, n, 100, 100);
}

// Round 4
// 235.191 us; speedup vs baseline: 19.3479x; 1.2762x over previous
//
#include <hip/hip_runtime.h>
#include <hip/hip_bf16.h>
#include <stdint.h>

typedef __bf16 bf16_t;
typedef bf16_t bf16x8 __attribute__((ext_vector_type(8)));
typedef float f32x4 __attribute__((ext_vector_type(4)));

#define NN 10000

__device__ __forceinline__ float b2f(unsigned short u) {
  union { unsigned int i; float f; } c; c.i = ((unsigned int)u) << 16; return c.f;
}
__device__ __forceinline__ unsigned short f2b(float f) {
  union { float f; unsigned int i; } c; c.f = f;
  unsigned int x = c.i;
  x += 0x7FFFu + ((x >> 16) & 1u);
  return (unsigned short)(x >> 16);
}

// async 16B global->LDS (m97 pattern; compiler never auto-emits this)
__device__ __forceinline__ void load_lds16(const void* g, void* l) {
  __builtin_amdgcn_global_load_lds(
      (const __attribute__((address_space(1))) unsigned int*)g,
      (__attribute__((address_space(3))) unsigned int*)l, 16, 0, 0);
}

// ---------------- fused prep: x->bf16, W1/W2/Wc transpose->bf16, edge degree ----------------
__global__ void prep(const float* __restrict__ x, const float* __restrict__ W1,
                     const float* __restrict__ W2, const float* __restrict__ Wc,
                     const int* __restrict__ dst, int* __restrict__ edeg,
                     unsigned short* __restrict__ xb, unsigned short* __restrict__ W1t,
                     unsigned short* __restrict__ W2t, unsigned short* __restrict__ Wct, int E) {
  int t = blockIdx.x * 256 + threadIdx.x;
  const int XN = NN * 512;
  if (t < XN) { xb[t] = f2b(x[t]); return; }
  t -= XN;
  if (t < 512 * 512) { int nn = t >> 9, k = t & 511; W1t[t] = f2b(W1[k * 512 + nn]); return; }
  t -= 512 * 512;
  if (t < 512 * 512) { int nn = t >> 9, k = t & 511; W2t[t] = f2b(W2[k * 512 + nn]); return; }
  t -= 512 * 512;
  if (t < 128 * 512) { int nn = t >> 9, k = t & 511; Wct[t] = (nn < 100) ? f2b(Wc[k * 100 + nn]) : (unsigned short)0; return; }
  t -= 128 * 512;
  if (t < E) atomicAdd(&edeg[dst[t]], 1);
}

// single-block: exclusive scan edeg -> rowstart, dinv = rsqrt(1+deg), edeg -> 0 (fill cursor)
__global__ void csr_scan(int* __restrict__ edeg, int* __restrict__ rowstart,
                         float* __restrict__ dinv, int n) {
  __shared__ int partial[256];
  const int t = threadIdx.x;
  const int per = (n + 255) / 256;
  const int lo = t * per;
  const int hi = (lo + per < n) ? lo + per : n;
  int s = 0;
  for (int i = lo; i < hi; i++) s += edeg[i];
  partial[t] = s;
  __syncthreads();
  for (int off = 1; off < 256; off <<= 1) {
    int v = (t >= off) ? partial[t - off] : 0;
    __syncthreads();
    partial[t] += v;
    __syncthreads();
  }
  int run = (t > 0) ? partial[t - 1] : 0;
  for (int i = lo; i < hi; i++) {
    int d = edeg[i];
    rowstart[i] = run; run += d;
    dinv[i] = rsqrtf(1.0f + (float)d);
    edeg[i] = 0;
  }
  if (t == 255) rowstart[n] = run;
}

__global__ void csr_fill(const int* __restrict__ src, const int* __restrict__ dst,
                         const float* __restrict__ dinv, const int* __restrict__ rowstart,
                         int* __restrict__ cursor, int* __restrict__ csr_src,
                         float* __restrict__ csr_norm, int E) {
  int e = blockIdx.x * 256 + threadIdx.x;
  if (e >= E) return;
  int s = src[e], d = dst[e];
  int pos = rowstart[d] + atomicAdd(&cursor[d], 1);
  csr_src[pos] = s;
  csr_norm[pos] = dinv[s] * dinv[d];
}

// ---- GEMM: C[M][N] = A[M][512](bf16) * Bt[N][512]^T(bf16); C fp32 or bf16 ----
__device__ __forceinline__ f32x4 mfma16(bf16x8 a, bf16x8 b, f32x4 c) {
  return __builtin_amdgcn_mfma_f32_16x16x32_bf16(a, b, c, 0, 0, 0);
}

template <bool BIAS, bool OBF16>
__global__ __launch_bounds__(256)
void gemm_bb(const unsigned short* __restrict__ A, const unsigned short* __restrict__ Bt,
             void* __restrict__ Cv, const float* __restrict__ bias,
             int M, int Ncols, int ldc)
{
  __shared__ __align__(16) unsigned short As[128 * 32];
  __shared__ __align__(16) unsigned short Bs[128 * 32];
  const int tid = threadIdx.x;
  const int lane = tid & 63;
  const int wm = (tid >> 6) >> 1;
  const int wn = (tid >> 6) & 1;
  const int tm = blockIdx.x, tn = blockIdx.y;
  const int quad = lane >> 4, l15 = lane & 15;

  // staging map: thread tid -> LDS byte offset tid*16 (wave-contiguous, required by global_load_lds)
  const int r0 = tid >> 2, kc = tid & 3;
  int ga0 = tm * 128 + r0;       if (ga0 > M - 1) ga0 = M - 1;
  int ga1 = tm * 128 + 64 + r0;  if (ga1 > M - 1) ga1 = M - 1;
  const int gb0 = tn * 128 + r0;
  const int gb1 = tn * 128 + 64 + r0;
  const unsigned short* gA0 = A + (size_t)ga0 * 512 + kc * 8;
  const unsigned short* gA1 = A + (size_t)ga1 * 512 + kc * 8;
  const unsigned short* gB0 = Bt + (size_t)gb0 * 512 + kc * 8;
  const unsigned short* gB1 = Bt + (size_t)gb1 * 512 + kc * 8;
  unsigned short* lA0 = &As[r0 * 32 + kc * 8];
  unsigned short* lA1 = &As[(64 + r0) * 32 + kc * 8];
  unsigned short* lB0 = &Bs[r0 * 32 + kc * 8];
  unsigned short* lB1 = &Bs[(64 + r0) * 32 + kc * 8];

  f32x4 acc[4][4];
  #pragma unroll
  for (int i = 0; i < 4; i++)
    #pragma unroll
    for (int j = 0; j < 4; j++) {
      f32x4 z = {0.f, 0.f, 0.f, 0.f};
      acc[i][j] = z;
    }

  for (int k0 = 0; k0 < 512; k0 += 32) {
    __syncthreads();           // previous iter's ds_reads complete before overwrite
    load_lds16(gA0 + k0, lA0);
    load_lds16(gA1 + k0, lA1);
    load_lds16(gB0 + k0, lB0);
    load_lds16(gB1 + k0, lB1);
    __syncthreads();           // drains vmcnt (global_load_lds) for all waves

    bf16x8 af[4], bfr[4];
    #pragma unroll
    for (int i = 0; i < 4; i++) {
      af[i]  = *(const bf16x8*)&As[(wm * 64 + i * 16 + l15) * 32 + quad * 8];
      bfr[i] = *(const bf16x8*)&Bs[(wn * 64 + i * 16 + l15) * 32 + quad * 8];
    }
    #pragma unroll
    for (int i = 0; i < 4; i++)
      #pragma unroll
      for (int j = 0; j < 4; j++)
        acc[i][j] = mfma16(af[i], bfr[j], acc[i][j]);
  }

  // epilogue: C/D layout col=lane&15, row=quad*4+reg  [m89-verified]
  #pragma unroll
  for (int i = 0; i < 4; i++) {
    const int row_base = tm * 128 + wm * 64 + i * 16 + quad * 4;
    #pragma unroll
    for (int j = 0; j < 4; j++) {
      const int col = tn * 128 + wn * 64 + j * 16 + l15;
      if (col < Ncols) {
        float badd = BIAS ? bias[col] : 0.f;
        #pragma unroll
        for (int r = 0; r < 4; r++) {
          int row = row_base + r;
          if (row < M) {
            float v = acc[i][j][r] + badd;
            if (OBF16) ((unsigned short*)Cv)[(size_t)row * ldc + col] = f2b(v);
            else       ((float*)Cv)[(size_t)row * ldc + col] = v;
          }
        }
      }
    }
  }
}

// ------ gather aggregation (bf16 rows): one wave per dst node, 4-edge unroll ------
__device__ __forceinline__ void acc8(float* a, uint4 v, float nm) {
  a[0] = fmaf(b2f((unsigned short)(v.x & 0xffffu)), nm, a[0]);
  a[1] = fmaf(b2f((unsigned short)(v.x >> 16)),     nm, a[1]);
  a[2] = fmaf(b2f((unsigned short)(v.y & 0xffffu)), nm, a[2]);
  a[3] = fmaf(b2f((unsigned short)(v.y >> 16)),     nm, a[3]);
  a[4] = fmaf(b2f((unsigned short)(v.z & 0xffffu)), nm, a[4]);
  a[5] = fmaf(b2f((unsigned short)(v.z >> 16)),     nm, a[5]);
  a[6] = fmaf(b2f((unsigned short)(v.w & 0xffffu)), nm, a[6]);
  a[7] = fmaf(b2f((unsigned short)(v.w >> 16)),     nm, a[7]);
}

template <bool RELU>
__global__ __launch_bounds__(256)
void gather_agg(const unsigned short* __restrict__ h, const float* __restrict__ dinv,
                const int* __restrict__ rowstart, const int* __restrict__ csr_src,
                const float* __restrict__ csr_norm, const float* __restrict__ bias,
                unsigned short* __restrict__ outb, int n)
{
  int node = blockIdx.x * 4 + (threadIdx.x >> 6);
  if (node >= n) return;
  const int lane = threadIdx.x & 63;
  const int c8 = lane * 8;

  float di = dinv[node];
  float slf = di * di;
  uint4 hv = *(const uint4*)&h[(size_t)node * 512 + c8];
  const float4* bp = (const float4*)&bias[c8];
  float4 b0 = bp[0], b1 = bp[1];
  float a[8] = {b0.x, b0.y, b0.z, b0.w, b1.x, b1.y, b1.z, b1.w};
  acc8(a, hv, slf);

  const int jb = rowstart[node], je = rowstart[node + 1];
  int j = jb;
  for (; j + 4 <= je; j += 4) {
    int s0 = csr_src[j], s1 = csr_src[j + 1], s2 = csr_src[j + 2], s3 = csr_src[j + 3];
    float n0 = csr_norm[j], n1 = csr_norm[j + 1], n2 = csr_norm[j + 2], n3 = csr_norm[j + 3];
    uint4 v0 = *(const uint4*)&h[(size_t)s0 * 512 + c8];
    uint4 v1 = *(const uint4*)&h[(size_t)s1 * 512 + c8];
    uint4 v2 = *(const uint4*)&h[(size_t)s2 * 512 + c8];
    uint4 v3 = *(const uint4*)&h[(size_t)s3 * 512 + c8];
    acc8(a, v0, n0); acc8(a, v1, n1); acc8(a, v2, n2); acc8(a, v3, n3);
  }
  for (; j < je; ++j) {
    int s = csr_src[j];
    float nm = csr_norm[j];
    uint4 v = *(const uint4*)&h[(size_t)s * 512 + c8];
    acc8(a, v, nm);
  }
  if (RELU) {
    #pragma unroll
    for (int q = 0; q < 8; q++) a[q] = fmaxf(a[q], 0.f);
  }
  uint4 o;
  o.x = (unsigned int)f2b(a[0]) | ((unsigned int)f2b(a[1]) << 16);
  o.y = (unsigned int)f2b(a[2]) | ((unsigned int)f2b(a[3]) << 16);
  o.z = (unsigned int)f2b(a[4]) | ((unsigned int)f2b(a[5]) << 16);
  o.w = (unsigned int)f2b(a[6]) | ((unsigned int)f2b(a[7]) << 16);
  *(uint4*)&outb[(size_t)node * 512 + c8] = o;
}

extern "C" void kernel_launch(void* const* d_in, const int* in_sizes, int n_in,
                              void* d_out, int out_size, void* d_ws, size_t ws_size,
                              hipStream_t stream) {
  const float* x  = (const float*)d_in[0];
  const int*   ei = (const int*)d_in[1];
  const float* W1 = (const float*)d_in[2];
  const float* b1 = (const float*)d_in[3];
  const float* W2 = (const float*)d_in[4];
  const float* b2 = (const float*)d_in[5];
  const float* Wc = (const float*)d_in[6];
  const float* bc = (const float*)d_in[7];
  float* out = (float*)d_out;

  const int n = NN;
  const int E = in_sizes[1] / 2;
  const int* src = ei;
  const int* dst = ei + E;

  // workspace (~33 MB)
  char* w = (char*)d_ws;
  float* dinv = (float*)w;                  w += ((n * 4 + 255) / 256) * 256;
  int* edeg = (int*)w;                      w += ((n * 4 + 255) / 256) * 256;   // also fill cursor
  int* rowstart = (int*)w;                  w += (((n + 1) * 4 + 255) / 256) * 256;
  int* csr_src = (int*)w;                   w += ((E * 4 + 255) / 256) * 256;
  float* csr_norm = (float*)w;              w += ((E * 4 + 255) / 256) * 256;
  unsigned short* xb  = (unsigned short*)w; w += (size_t)n * 512 * 2;
  unsigned short* W1t = (unsigned short*)w; w += 512 * 512 * 2;
  unsigned short* W2t = (unsigned short*)w; w += 512 * 512 * 2;
  unsigned short* Wct = (unsigned short*)w; w += 128 * 512 * 2;
  unsigned short* B1  = (unsigned short*)w; w += (size_t)n * 512 * 2;  // agg out / next A
  unsigned short* B2  = (unsigned short*)w; w += (size_t)n * 512 * 2;  // h (pre-agg)

  const int nb_e = (E + 255) / 256;
  const int prep_items = n * 512 + 512 * 512 * 2 + 128 * 512 + E;
  const int nb_prep = (prep_items + 255) / 256;
  dim3 g1((n + 127) / 128, 4);
  dim3 g3((n + 127) / 128, 1);
  const int nb_g = (n + 3) / 4;

  hipMemsetAsync(edeg, 0, n * sizeof(int), stream);
  prep<<<nb_prep, 256, 0, stream>>>(x, W1, W2, Wc, dst, edeg, xb, W1t, W2t, Wct, E);
  csr_scan<<<1, 256, 0, stream>>>(edeg, rowstart, dinv, n);
  csr_fill<<<nb_e, 256, 0, stream>>>(src, dst, dinv, rowstart, edeg, csr_src, csr_norm, E);

  // layer 1
  gemm_bb<false, true><<<g1, 256, 0, stream>>>(xb, W1t, B2, nullptr, n, 512, 512);
  gather_agg<true><<<nb_g, 256, 0, stream>>>(B2, dinv, rowstart, csr_src, csr_norm, b1, B1, n);

  // layer 2
  gemm_bb<false, true><<<g1, 256, 0, stream>>>(B1, W2t, B2, nullptr, n, 512, 512);
  gather_agg<false><<<nb_g, 256, 0, stream>>>(B2, dinv, rowstart, csr_src, csr_norm, b2, B1, n);

  // classifier (fp32 out)
  gemm_bb<true, false><<<g3, 256, 0, stream>>>(B1, Wct, out, bc, n, 100, 100);
}